// Round 2
// baseline (189.604 us; speedup 1.0000x reference)
//
#include <hip/hip_runtime.h>
#include <cstdint>

#define B_SZ 8192
#define D_SZ 512
#define K_SZ 2048
#define EPSV 1e-8f
// 1/TEMP
#define INV_T 2.0f

typedef float floatx16 __attribute__((ext_vector_type(16)));
typedef int intx8 __attribute__((ext_vector_type(8)));

// async global->LDS, 16B per lane. LDS dest must be wave-uniform base + lane*16.
// Global SOURCE address is per-lane (guide §5) -> gather at stage time is free.
__device__ __forceinline__ void async_cp16(const void* g, void* l) {
    typedef __attribute__((address_space(1))) unsigned int gds_t;
    typedef __attribute__((address_space(3))) unsigned int lds_t;
    __builtin_amdgcn_global_load_lds((gds_t*)(unsigned long long)g, (lds_t*)l, 16, 0, 0);
}

// pack 8 fp32 -> 8 fp8 e4m3 (OCP, RNE, saturating) as int2
__device__ __forceinline__ int2 pack_fp8x8(float4 a0, float4 a1) {
    int w0 = __builtin_amdgcn_cvt_pk_fp8_f32(a0.x, a0.y, 0, false);
    w0 = __builtin_amdgcn_cvt_pk_fp8_f32(a0.z, a0.w, w0, true);
    int w1 = __builtin_amdgcn_cvt_pk_fp8_f32(a1.x, a1.y, 0, false);
    w1 = __builtin_amdgcn_cvt_pk_fp8_f32(a1.z, a1.w, w1, true);
    return make_int2(w0, w1);
}

// ---------------------------------------------------------------------------
// Kernel 1 (R12): UNIFORM prep — 2048 blocks x 256 thr, 4 rows each.
// Per row: ni, nj, pos; pack z_i -> A (fp8) AND z_j -> ZJ8 (fp8, all 8192
// rows). The gather pass is gone — k_gemm gathers from ZJ8 directly via
// per-lane global_load_lds source addresses. Also zeroes rowacc/tickets/out
// (harness re-poisons ws with 0xAA every iteration).
// ---------------------------------------------------------------------------
__global__ __launch_bounds__(256) void k_prep(
    const float* __restrict__ zi, const float* __restrict__ zj,
    float* __restrict__ ri_arr, float* __restrict__ rj_arr,
    float* __restrict__ pos_arr,
    unsigned char* __restrict__ A, unsigned char* __restrict__ ZJ8,
    float* __restrict__ rowacc, int* __restrict__ tickets,
    float* __restrict__ out)
{
    int w = threadIdx.x >> 6, l = threadIdx.x & 63;
    if (blockIdx.x < 64)
        rowacc[blockIdx.x * 256 + threadIdx.x] = 0.f;   // pe[8192] ++ pc[8192]
    if (blockIdx.x == 64 && threadIdx.x < 32) tickets[threadIdx.x] = 0;
    if (blockIdx.x == 0 && threadIdx.x < 3) out[threadIdx.x] = 0.f;

    int row = blockIdx.x * 4 + w;
    const float4* zi4 = (const float4*)(zi + (size_t)row * D_SZ);
    const float4* zj4 = (const float4*)(zj + (size_t)row * D_SZ);
    float4 a0 = zi4[2 * l], a1 = zi4[2 * l + 1];
    float4 b0 = zj4[2 * l], b1 = zj4[2 * l + 1];
    float si = a0.x * a0.x + a0.y * a0.y + a0.z * a0.z + a0.w * a0.w
             + a1.x * a1.x + a1.y * a1.y + a1.z * a1.z + a1.w * a1.w;
    float sj = b0.x * b0.x + b0.y * b0.y + b0.z * b0.z + b0.w * b0.w
             + b1.x * b1.x + b1.y * b1.y + b1.z * b1.z + b1.w * b1.w;
    float dd = a0.x * b0.x + a0.y * b0.y + a0.z * b0.z + a0.w * b0.w
             + a1.x * b1.x + a1.y * b1.y + a1.z * b1.z + a1.w * b1.w;
    for (int m = 1; m < 64; m <<= 1) {
        si += __shfl_xor(si, m);
        sj += __shfl_xor(sj, m);
        dd += __shfl_xor(dd, m);
    }
    if (l == 0) {
        float ni = sqrtf(si), nj = sqrtf(sj);
        ri_arr[row] = INV_T / fmaxf(ni, 1e-6f);   // norms ~22; eps never binds
        rj_arr[row] = 1.0f / fmaxf(nj, 1e-6f);    // same clamp the gather used
        pos_arr[row] = dd / fmaxf(ni * nj, EPSV) * INV_T;
    }
    *(int2*)(A   + (size_t)row * D_SZ + l * 8) = pack_fp8x8(a0, a1);
    *(int2*)(ZJ8 + (size_t)row * D_SZ + l * 8) = pack_fp8x8(b0, b1);
}

// ---------------------------------------------------------------------------
// Kernel 2 (R12): MX-fp8 MFMA GEMM, S^T = G . A^T, 256x256 tile, 8 waves,
// 3-deep LDS ring + counted vmcnt(4) + one raw s_barrier per K-step +
// lgkmcnt(0)+sched_barrier(0) (rule #18) + setprio around the MFMA cluster.
// NEW vs R1 (schedule byte-identical):
//  - B-operand gathered from ZJ8 at stage time (per-lane global src addr);
//    the G buffer and the prep gather pass are gone.
//  - per-block kmeta table kms[128] built in the PROLOGUE from perm/rj_arr;
//    its global loads are drained with vmcnt(0) BEFORE the first STAGE so
//    the K-loop's counted vmcnt(4) still counts only STAGE groups.
//  - k_final merged in via last-block ticket per aTile (16 blocks/aTile):
//    threadfence -> syncthreads -> ticket; ticket==15 finalizes 256 rows
//    (agent-scope atomic loads of rowacc). Same row partition and in-block
//    summation order as the old k_final.
// ---------------------------------------------------------------------------
__global__ __launch_bounds__(512, 2) void k_gemm(
    const unsigned char* __restrict__ A,    // [8192][512] fp8  (anchors)
    const unsigned char* __restrict__ ZJ8,  // [8192][512] fp8  (all z_j rows)
    const int* __restrict__ perm,           // [2048]
    const float* __restrict__ ri_arr,       // [8192]  INV_T/ni
    const float* __restrict__ rj_arr,       // [8192]  1/nj
    const float* __restrict__ pos_arr,      // [8192]
    float* __restrict__ rowacc,             // [2][8192] atomic accumulators
    int* __restrict__ tickets,              // [32] per-aTile completion
    float* __restrict__ out)                // [3] loss, acc1, acc5
{
    __shared__ unsigned char Asl[3][256 * 64];   // anchor tiles, 16 KB each
    __shared__ unsigned char Gsl[3][256 * 64];   // gathered-neg tiles
    __shared__ float4 kms[128];                  // {rj0, rj1, c0f, -} per local k
    __shared__ int doFin;
    __shared__ float red[3][8];
    const int tid = threadIdx.x;
    const int l = tid & 63, w = tid >> 6;
    const int wm = w >> 2, wn = w & 3;      // wm: g-half (0..1), wn: anchor quarter
    const int ln = l & 31, q = l >> 5;      // 32x32 MFMA lane decomposition

    // XCD-aware tile mapping: 512 blocks; xcd = bid&7 owns g-panels xcd*2..+2
    const int bid = blockIdx.x;
    const int xcd = bid & 7;
    const int slot = bid >> 3;              // 0..63
    const int gTile = xcd * 2 + (slot & 1); // 0..15 (neg panel, 256 g-rows)
    const int aTile = slot >> 1;            // 0..31 (anchor panel, 256 rows)
    const int gBase = gTile * 256;
    const int aBase = aTile * 256;

    // staging offsets (bytes); 1024 16B-chunks per array per K-block
    // (2 iters x 512 threads). Same XOR swizzle as R10/R11 (0 conflicts).
    // G source row is the permuted z_j row: g=gBase+r -> perm[g>>1]+(g&1).
    size_t aOff[2], gOff[2];
    int ldsOff[2];
    #pragma unroll
    for (int it = 0; it < 2; ++it) {
        int fc = it * 512 + tid;            // 16B chunk 0..1023
        int r = fc >> 2, s = fc & 3;
        int scc = s ^ ((r ^ (r >> 2)) & 3); // XOR swizzle source 16B chunk
        aOff[it] = (size_t)(aBase + r) * D_SZ + scc * 16;
        int g = gBase + r;
        int zjRow = perm[g >> 1] + (g & 1);
        gOff[it] = (size_t)zjRow * D_SZ + scc * 16;
        ldsOff[it] = fc * 16;
    }

    floatx16 acc[4][2] = {};                // [tm: g-subtile][tn: anchor-subtile]

    // frag read addresses (bytes in a 16 KB buffer): lane needs k-bytes
    // [q*32, q*32+32) of its row = pre-swizzle chunks {2q, 2q+1}
    int aAddr[2][2], gAddr[4][2];
    #pragma unroll
    for (int tn = 0; tn < 2; ++tn) {
        int ar = wn * 64 + tn * 32 + ln;    // anchor row in tile (N-operand)
        int xa = (ar ^ (ar >> 2)) & 3;
        aAddr[tn][0] = ar * 64 + ((2 * q) ^ xa) * 16;
        aAddr[tn][1] = ar * 64 + ((2 * q + 1) ^ xa) * 16;
    }
    #pragma unroll
    for (int tm = 0; tm < 4; ++tm) {
        int gr = wm * 128 + tm * 32 + ln;   // g row in tile (M-operand)
        int xg = (gr ^ (gr >> 2)) & 3;
        gAddr[tm][0] = gr * 64 + ((2 * q) ^ xg) * 16;
        gAddr[tm][1] = gr * 64 + ((2 * q + 1) ^ xg) * 16;
    }

    // per-block kmeta table: local k 0..127 -> {rj(c0), rj(c0+1), c0}
    if (tid < 128) {
        int k = gTile * 128 + tid;
        int c0 = perm[k];
        kms[tid] = make_float4(rj_arr[c0], rj_arr[c0 + 1],
                               __int_as_float(c0), 0.f);
    }
    // Drain the kms/perm global loads so the K-loop's counted vmcnt(4)
    // tracks ONLY the STAGE groups (vmcnt is a single in-order counter).
    asm volatile("s_waitcnt vmcnt(0)" ::: "memory");
    __builtin_amdgcn_sched_barrier(0);

    // stage K-block kb into ring buffer `buf` (4 async_cp16 per thread)
    auto STAGE = [&](int buf, int kb) {
        #pragma unroll
        for (int it = 0; it < 2; ++it) {
            async_cp16(A   + aOff[it] + (size_t)kb * 64, &Asl[buf][ldsOff[it]]);
            async_cp16(ZJ8 + gOff[it] + (size_t)kb * 64, &Gsl[buf][ldsOff[it]]);
        }
    };

    // prologue: fill first two ring slots
    STAGE(0, 0);
    STAGE(1, 1);

    #pragma unroll
    for (int kb = 0; kb < 8; ++kb) {
        const int cur = kb % 3;
        // wait for buf[cur]'s 4 stage loads (the newest 4 = next K-block stay
        // in flight -- NEVER drain vmcnt to 0 mid-loop). vmcnt is in-order.
        if (kb < 7) {
            asm volatile("s_waitcnt vmcnt(4)" ::: "memory");
        } else {
            asm volatile("s_waitcnt vmcnt(0)" ::: "memory");
        }
        __builtin_amdgcn_s_barrier();       // ALL waves' DMA for cur landed;
                                            // all waves done reading the slot we overwrite
        if (kb < 6) STAGE((kb + 2) % 3, kb + 2);   // overwrite oldest slot

        intx8 af[2], gf[4];
        #pragma unroll
        for (int tn = 0; tn < 2; ++tn) {
            int4 lo = *(const int4*)&Asl[cur][aAddr[tn][0]];
            int4 hi = *(const int4*)&Asl[cur][aAddr[tn][1]];
            af[tn][0] = lo.x; af[tn][1] = lo.y; af[tn][2] = lo.z; af[tn][3] = lo.w;
            af[tn][4] = hi.x; af[tn][5] = hi.y; af[tn][6] = hi.z; af[tn][7] = hi.w;
        }
        #pragma unroll
        for (int tm = 0; tm < 4; ++tm) {
            int4 lo = *(const int4*)&Gsl[cur][gAddr[tm][0]];
            int4 hi = *(const int4*)&Gsl[cur][gAddr[tm][1]];
            gf[tm][0] = lo.x; gf[tm][1] = lo.y; gf[tm][2] = lo.z; gf[tm][3] = lo.w;
            gf[tm][4] = hi.x; gf[tm][5] = hi.y; gf[tm][6] = hi.z; gf[tm][7] = hi.w;
        }
        // reads must retire before next iter's barrier (so STAGE can overwrite)
        asm volatile("s_waitcnt lgkmcnt(0)" ::: "memory");
        __builtin_amdgcn_sched_barrier(0);  // rule #18: pin MFMA after the wait

        __builtin_amdgcn_s_setprio(1);      // T5: favor the MFMA cluster
        #pragma unroll
        for (int tm = 0; tm < 4; ++tm)
            #pragma unroll
            for (int tn = 0; tn < 2; ++tn)
                acc[tm][tn] = __builtin_amdgcn_mfma_scale_f32_32x32x64_f8f6f4(
                    gf[tm], af[tn], acc[tm][tn],
                    0, 0,                       // cbsz/blgp = fp8 e4m3
                    0, 0x7f7f7f7f,              // scale A: all-ones (2^0)
                    0, 0x7f7f7f7f);             // scale B: all-ones (2^0)
        __builtin_amdgcn_s_setprio(0);
    }

    // ---- fused epilogue: pair-select then exp, in-register reduction ----
    // C/D layout (32x32): col = anchor = ln (+tn*32), row = g = (reg&3) +
    // 8*(reg>>2) + 4*q (+tm*32 +wm*128). Regs 4j..4j+3 hold 4 consecutive g,
    // i.e. local column pairs kidx = wm*64 + tm*16 + 4j + 2q and kidx+1.
    int anc[2]; float riv[2], pv[2], pe[2] = {0.f, 0.f}, pc[2] = {0.f, 0.f};
    #pragma unroll
    for (int tn = 0; tn < 2; ++tn) {
        anc[tn] = aBase + wn * 64 + tn * 32 + ln;
        riv[tn] = ri_arr[anc[tn]];          // INV_T / ni
        pv[tn] = pos_arr[anc[tn]];
    }
    #pragma unroll
    for (int tm = 0; tm < 4; ++tm) {
        #pragma unroll
        for (int j = 0; j < 4; ++j) {
            int kidx = wm * 64 + tm * 16 + 4 * j + 2 * q;   // local k in [0,128)
            float4 m0 = kms[kidx];
            float4 m1 = kms[kidx + 1];
            #pragma unroll
            for (int p = 0; p < 2; ++p) {
                float4 md = p ? m1 : m0;
                int c0 = __float_as_int(md.z);
                int re = 4 * j + 2 * p;     // even-g reg; odd is re+1
                #pragma unroll
                for (int tn = 0; tn < 2; ++tn) {
                    bool sel = (c0 >= anc[tn]);             // use column c0+1
                    float v = sel ? acc[tm][tn][re + 1] : acc[tm][tn][re];
                    float rj = sel ? md.y : md.x;
                    float logit = v * riv[tn] * rj;
                    pe[tn] += __expf(logit);
                    pc[tn] += (logit > pv[tn]) ? 1.f : 0.f;
                }
            }
        }
    }
    #pragma unroll
    for (int tn = 0; tn < 2; ++tn) {
        pe[tn] += __shfl_xor(pe[tn], 32);
        pc[tn] += __shfl_xor(pc[tn], 32);
        if (q == 0) {
            atomicAdd(&rowacc[anc[tn]], pe[tn]);
            atomicAdd(&rowacc[B_SZ + anc[tn]], pc[tn]);
        }
    }

    // ---- last-block finalize (merged k_final) ----
    __threadfence();                        // each wave drains its own atomics
    __syncthreads();                        // all waves' atomics device-visible
    if (tid == 0) {
        int t = atomicAdd(&tickets[aTile], 1);
        doFin = (t == 15);                  // 16 blocks (gTiles) per aTile
    }
    __syncthreads();
    if (doFin) {
        __threadfence();                    // acquire side
        float loss = 0.f, a1 = 0.f, a5 = 0.f;
        if (tid < 256) {
            int row = aBase + tid;
            float pes = __hip_atomic_load(&rowacc[row],
                                          __ATOMIC_RELAXED, __HIP_MEMORY_SCOPE_AGENT);
            float pcs = __hip_atomic_load(&rowacc[B_SZ + row],
                                          __ATOMIC_RELAXED, __HIP_MEMORY_SCOPE_AGENT);
            float pos = pos_arr[row];
            loss = logf(__expf(pos) + pes) - pos;  // logsumexp - pos (bounded)
            a1 = (pcs < 0.5f) ? 1.f : 0.f;         // no neg strictly > pos
            a5 = (pcs < 4.5f) ? 1.f : 0.f;         // at most 4 negs > pos
        }
        for (int m = 1; m < 64; m <<= 1) {
            loss += __shfl_xor(loss, m);
            a1 += __shfl_xor(a1, m);
            a5 += __shfl_xor(a5, m);
        }
        if (l == 0) { red[0][w] = loss; red[1][w] = a1; red[2][w] = a5; }
        __syncthreads();
        if (tid == 0) {
            float L = 0.f, A1 = 0.f, A5 = 0.f;
            #pragma unroll
            for (int i = 0; i < 8; ++i) {
                L += red[0][i]; A1 += red[1][i]; A5 += red[2][i];
            }
            atomicAdd(&out[0], L / (float)B_SZ);
            atomicAdd(&out[1], A1 * (100.f / (float)B_SZ));
            atomicAdd(&out[2], A5 * (100.f / (float)B_SZ));
        }
    }
}

// ---------------------------------------------------------------------------
extern "C" void kernel_launch(void* const* d_in, const int* in_sizes, int n_in,
                              void* d_out, int out_size, void* d_ws, size_t ws_size,
                              hipStream_t stream)
{
    const float* zi = (const float*)d_in[0];
    const float* zj = (const float*)d_in[1];
    const int* perm = (const int*)d_in[2];
    float* out = (float*)d_out;

    // workspace layout (all 16B aligned)
    char* p = (char*)d_ws;
    unsigned char* A = (unsigned char*)p;    p += (size_t)B_SZ * D_SZ;          // 4 MB
    unsigned char* ZJ8 = (unsigned char*)p;  p += (size_t)B_SZ * D_SZ;          // 4 MB
    float* ri_arr = (float*)p;               p += (size_t)B_SZ * 4;
    float* rj_arr = (float*)p;               p += (size_t)B_SZ * 4;
    float* pos_arr = (float*)p;              p += (size_t)B_SZ * 4;
    float* rowacc = (float*)p;               p += (size_t)2 * B_SZ * 4;         // 64 KB
    int* tickets = (int*)p;                  p += 128;

    k_prep<<<2048, 256, 0, stream>>>(zi, zj, ri_arr, rj_arr, pos_arr,
                                     A, ZJ8, rowacc, tickets, out);
    k_gemm<<<512, 512, 0, stream>>>(A, ZJ8, perm, ri_arr, rj_arr, pos_arr,
                                    rowacc, tickets, out);
}

// Round 3
// 119.670 us; speedup vs baseline: 1.5844x; 1.5844x over previous
//
#include <hip/hip_runtime.h>
#include <cstdint>

#define B_SZ 8192
#define D_SZ 512
#define K_SZ 2048
#define EPSV 1e-8f
// 1/TEMP
#define INV_T 2.0f

typedef float floatx16 __attribute__((ext_vector_type(16)));
typedef int intx8 __attribute__((ext_vector_type(8)));

// async global->LDS, 16B per lane. LDS dest must be wave-uniform base + lane*16.
// NOTE (R2 lesson): global source must stay COALESCED — scattered per-lane row
// gathers serialize the LDS-DMA per cache line and put that latency on the
// counted-vmcnt critical path (126 us regression).
__device__ __forceinline__ void async_cp16(const void* g, void* l) {
    typedef __attribute__((address_space(1))) unsigned int gds_t;
    typedef __attribute__((address_space(3))) unsigned int lds_t;
    __builtin_amdgcn_global_load_lds((gds_t*)(unsigned long long)g, (lds_t*)l, 16, 0, 0);
}

// pack 8 fp32 -> 8 fp8 e4m3 (OCP, RNE, saturating) as int2
__device__ __forceinline__ int2 pack_fp8x8(float4 a0, float4 a1) {
    int w0 = __builtin_amdgcn_cvt_pk_fp8_f32(a0.x, a0.y, 0, false);
    w0 = __builtin_amdgcn_cvt_pk_fp8_f32(a0.z, a0.w, w0, true);
    int w1 = __builtin_amdgcn_cvt_pk_fp8_f32(a1.x, a1.y, 0, false);
    w1 = __builtin_amdgcn_cvt_pk_fp8_f32(a1.z, a1.w, w1, true);
    return make_int2(w0, w1);
}

// ---------------------------------------------------------------------------
// Kernel 1 (reverted to R1, + tickets zeroing): merged prep+gather.
//  blocks [0,2048):  per-row norms of z_i/z_j, positive logit, z_i -> fp8 A.
//  blocks [2048,3072): gather 2K=4096 rows (c_k, c_k+1) of z_j -> fp8 G
//    (CONTIGUOUS — R2 showed gathering inside k_gemm's DMA path is fatal) +
//    per-column-pair metadata kmeta[k] = {1/nj(c), 1/nj(c+1), c0}.
// ---------------------------------------------------------------------------
__global__ __launch_bounds__(256) void k_prep(
    const float* __restrict__ zi, const float* __restrict__ zj,
    const int* __restrict__ perm,
    float* __restrict__ ri_arr, float* __restrict__ pos_arr,
    unsigned char* __restrict__ A,
    float4* __restrict__ kmeta, unsigned char* __restrict__ G,
    float* __restrict__ rowacc, int* __restrict__ tickets,
    float* __restrict__ out)
{
    int w = threadIdx.x >> 6, l = threadIdx.x & 63;
    if (blockIdx.x < 2048) {
        if (blockIdx.x < 64)
            rowacc[blockIdx.x * 256 + threadIdx.x] = 0.f;   // pe[8192] ++ pc[8192]
        if (blockIdx.x == 64 && threadIdx.x < 32) tickets[threadIdx.x] = 0;
        if (blockIdx.x == 0 && threadIdx.x < 3) out[threadIdx.x] = 0.f;
        int row = blockIdx.x * 4 + w;
        const float4* zi4 = (const float4*)(zi + (size_t)row * D_SZ);
        const float4* zj4 = (const float4*)(zj + (size_t)row * D_SZ);
        float4 a0 = zi4[2 * l], a1 = zi4[2 * l + 1];
        float4 b0 = zj4[2 * l], b1 = zj4[2 * l + 1];
        float si = a0.x * a0.x + a0.y * a0.y + a0.z * a0.z + a0.w * a0.w
                 + a1.x * a1.x + a1.y * a1.y + a1.z * a1.z + a1.w * a1.w;
        float sj = b0.x * b0.x + b0.y * b0.y + b0.z * b0.z + b0.w * b0.w
                 + b1.x * b1.x + b1.y * b1.y + b1.z * b1.z + b1.w * b1.w;
        float dd = a0.x * b0.x + a0.y * b0.y + a0.z * b0.z + a0.w * b0.w
                 + a1.x * b1.x + a1.y * b1.y + a1.z * b1.z + a1.w * b1.w;
        for (int m = 1; m < 64; m <<= 1) {
            si += __shfl_xor(si, m);
            sj += __shfl_xor(sj, m);
            dd += __shfl_xor(dd, m);
        }
        if (l == 0) {
            float ni = sqrtf(si), nj = sqrtf(sj);
            ri_arr[row] = INV_T / fmaxf(ni, 1e-6f);   // norms ~22; eps never binds
            pos_arr[row] = dd / fmaxf(ni * nj, EPSV) * INV_T;
        }
        *(int2*)(A + (size_t)row * D_SZ + l * 8) = pack_fp8x8(a0, a1);
    } else {
        __shared__ float srj[4];
        int g = (blockIdx.x - 2048) * 4 + w;        // 0..4095
        int c0 = perm[g >> 1];
        int c = c0 + (g & 1);                       // actual z_j row
        const float4* src = (const float4*)(zj + (size_t)c * D_SZ);
        float4 a0 = src[2 * l], a1 = src[2 * l + 1];
        float s = a0.x * a0.x + a0.y * a0.y + a0.z * a0.z + a0.w * a0.w
                + a1.x * a1.x + a1.y * a1.y + a1.z * a1.z + a1.w * a1.w;
        for (int m = 1; m < 64; m <<= 1) s += __shfl_xor(s, m);
        if (l == 0) srj[w] = 1.0f / fmaxf(sqrtf(s), 1e-6f);
        __syncthreads();
        if ((w & 1) == 0 && l == 0)
            kmeta[g >> 1] = make_float4(srj[w], srj[w + 1],
                                        __int_as_float(c0), 0.f);
        *(int2*)(G + (size_t)g * D_SZ + l * 8) = pack_fp8x8(a0, a1);
    }
}

// ---------------------------------------------------------------------------
// Kernel 2 (R13): MX-fp8 MFMA GEMM, S^T = G . A^T, 256x256 tile, 8 waves.
// Changes vs R1 (the 112.3-us verified version):
//  - 4-deep LDS ring (4 x 32 KB = 128 KB): 3 K-steps of prefetch lookahead
//    (was 2). Steady-state wait is vmcnt(8); never drained mid-loop.
//  - ALL epilogue global loads hoisted to the prologue (kmeta tile -> LDS
//    kms[128]; ri/pos -> regs), drained with vmcnt(0) BEFORE the first
//    STAGE. K-loop body now has ZERO compiler-visible VMEM besides STAGE,
//    so the counted vmcnt arithmetic is airtight (in R0/R1 the unrolled
//    loop let the compiler schedule 18 scattered epilogue loads into the
//    loop, corrupting the counts).
//  - merged finalize via acq-rel ticket (NO __threadfence / L2 writeback):
//    __syncthreads() drains each block's atomics; release-ordering on the
//    ticket makes them visible; 16th block per aTile finalizes 256 rows.
// ---------------------------------------------------------------------------
__global__ __launch_bounds__(512, 2) void k_gemm(
    const unsigned char* __restrict__ A,    // [8192][512] fp8  (anchors)
    const unsigned char* __restrict__ G,    // [4096][512] fp8  (gathered)
    const float4* __restrict__ kmeta,       // [2048]  {rj0, rj1, c0f, -}
    const float* __restrict__ ri_arr,       // [8192]  INV_T/ni
    const float* __restrict__ pos_arr,      // [8192]
    float* __restrict__ rowacc,             // [2][8192] atomic accumulators
    int* __restrict__ tickets,              // [32] per-aTile completion
    float* __restrict__ out)                // [3] loss, acc1, acc5
{
    __shared__ unsigned char Asl[4][256 * 64];   // anchor tiles, 16 KB each
    __shared__ unsigned char Gsl[4][256 * 64];   // g tiles
    __shared__ float4 kms[128];                  // this gTile's kmeta slice
    __shared__ int doFin;
    __shared__ float red[3][8];
    const int tid = threadIdx.x;
    const int l = tid & 63, w = tid >> 6;
    const int wm = w >> 2, wn = w & 3;      // wm: g-half (0..1), wn: anchor quarter
    const int ln = l & 31, q = l >> 5;      // 32x32 MFMA lane decomposition

    // XCD-aware tile mapping: 512 blocks; xcd = bid&7 owns g-panels xcd*2..+2
    const int bid = blockIdx.x;
    const int xcd = bid & 7;
    const int slot = bid >> 3;              // 0..63
    const int gTile = xcd * 2 + (slot & 1); // 0..15 (G row panel, 256 rows)
    const int aTile = slot >> 1;            // 0..31 (anchor panel, 256 rows)
    const int gBase = gTile * 256;
    const int aBase = aTile * 256;

    // staging offsets (bytes); 1024 16B-chunks per array per K-block
    // (2 iters x 512 threads). Same XOR swizzle as R10/R11 (0 conflicts).
    size_t aOff[2], gOff[2];
    int ldsOff[2];
    #pragma unroll
    for (int it = 0; it < 2; ++it) {
        int fc = it * 512 + tid;            // 16B chunk 0..1023
        int r = fc >> 2, s = fc & 3;
        int scc = s ^ ((r ^ (r >> 2)) & 3); // XOR swizzle source 16B chunk
        aOff[it] = (size_t)(aBase + r) * D_SZ + scc * 16;
        gOff[it] = (size_t)(gBase + r) * D_SZ + scc * 16;
        ldsOff[it] = fc * 16;
    }

    floatx16 acc[4][2] = {};                // [tm: g-subtile][tn: anchor-subtile]

    // frag read addresses (bytes in a 16 KB buffer): lane needs k-bytes
    // [q*32, q*32+32) of its row = pre-swizzle chunks {2q, 2q+1}
    int aAddr[2][2], gAddr[4][2];
    #pragma unroll
    for (int tn = 0; tn < 2; ++tn) {
        int ar = wn * 64 + tn * 32 + ln;    // anchor row in tile (N-operand)
        int xa = (ar ^ (ar >> 2)) & 3;
        aAddr[tn][0] = ar * 64 + ((2 * q) ^ xa) * 16;
        aAddr[tn][1] = ar * 64 + ((2 * q + 1) ^ xa) * 16;
    }
    #pragma unroll
    for (int tm = 0; tm < 4; ++tm) {
        int gr = wm * 128 + tm * 32 + ln;   // g row in tile (M-operand)
        int xg = (gr ^ (gr >> 2)) & 3;
        gAddr[tm][0] = gr * 64 + ((2 * q) ^ xg) * 16;
        gAddr[tm][1] = gr * 64 + ((2 * q + 1) ^ xg) * 16;
    }

    // ---- prologue: ALL global loads the epilogue needs, then drain ----
    int anc[2]; float riv[2], pv[2];
    #pragma unroll
    for (int tn = 0; tn < 2; ++tn) {
        anc[tn] = aBase + wn * 64 + tn * 32 + ln;
        riv[tn] = ri_arr[anc[tn]];          // INV_T / ni
        pv[tn] = pos_arr[anc[tn]];
    }
    float4 kv = make_float4(0.f, 0.f, 0.f, 0.f);
    if (tid < 128) kv = kmeta[gTile * 128 + tid];
    // Drain: from here on, vmcnt counts ONLY the 4-load STAGE groups.
    asm volatile("s_waitcnt vmcnt(0)" ::: "memory");
    __builtin_amdgcn_sched_barrier(0);
    if (tid < 128) kms[tid] = kv;           // visible to all at first s_barrier

    // stage K-block kb into ring buffer `buf` (4 async_cp16 per thread)
    auto STAGE = [&](int buf, int kb) {
        #pragma unroll
        for (int it = 0; it < 2; ++it) {
            async_cp16(A + aOff[it] + (size_t)kb * 64, &Asl[buf][ldsOff[it]]);
            async_cp16(G + gOff[it] + (size_t)kb * 64, &Gsl[buf][ldsOff[it]]);
        }
    };

    // prologue: fill first three ring slots (lookahead = 3 K-steps)
    STAGE(0, 0);
    STAGE(1, 1);
    STAGE(2, 2);

    #pragma unroll
    for (int kb = 0; kb < 8; ++kb) {
        const int cur = kb & 3;
        // Retire group kb only; keep up to 2 newer 4-load groups in flight.
        // Outstanding at top of iter kb: groups kb..min(kb+2,7).
        if (kb <= 5) {
            asm volatile("s_waitcnt vmcnt(8)" ::: "memory");
        } else if (kb == 6) {
            asm volatile("s_waitcnt vmcnt(4)" ::: "memory");
        } else {
            asm volatile("s_waitcnt vmcnt(0)" ::: "memory");
        }
        __builtin_amdgcn_s_barrier();       // ALL waves' DMA for cur landed;
                                            // all waves done reading the slot we overwrite
        if (kb < 5) STAGE((kb + 3) & 3, kb + 3);   // overwrite oldest slot

        intx8 af[2], gf[4];
        #pragma unroll
        for (int tn = 0; tn < 2; ++tn) {
            int4 lo = *(const int4*)&Asl[cur][aAddr[tn][0]];
            int4 hi = *(const int4*)&Asl[cur][aAddr[tn][1]];
            af[tn][0] = lo.x; af[tn][1] = lo.y; af[tn][2] = lo.z; af[tn][3] = lo.w;
            af[tn][4] = hi.x; af[tn][5] = hi.y; af[tn][6] = hi.z; af[tn][7] = hi.w;
        }
        #pragma unroll
        for (int tm = 0; tm < 4; ++tm) {
            int4 lo = *(const int4*)&Gsl[cur][gAddr[tm][0]];
            int4 hi = *(const int4*)&Gsl[cur][gAddr[tm][1]];
            gf[tm][0] = lo.x; gf[tm][1] = lo.y; gf[tm][2] = lo.z; gf[tm][3] = lo.w;
            gf[tm][4] = hi.x; gf[tm][5] = hi.y; gf[tm][6] = hi.z; gf[tm][7] = hi.w;
        }
        // reads must retire before next iter's barrier (so STAGE can overwrite)
        asm volatile("s_waitcnt lgkmcnt(0)" ::: "memory");
        __builtin_amdgcn_sched_barrier(0);  // rule #18: pin MFMA after the wait

        __builtin_amdgcn_s_setprio(1);      // T5: favor the MFMA cluster
        #pragma unroll
        for (int tm = 0; tm < 4; ++tm)
            #pragma unroll
            for (int tn = 0; tn < 2; ++tn)
                acc[tm][tn] = __builtin_amdgcn_mfma_scale_f32_32x32x64_f8f6f4(
                    gf[tm], af[tn], acc[tm][tn],
                    0, 0,                       // cbsz/blgp = fp8 e4m3
                    0, 0x7f7f7f7f,              // scale A: all-ones (2^0)
                    0, 0x7f7f7f7f);             // scale B: all-ones (2^0)
        __builtin_amdgcn_s_setprio(0);
    }

    // ---- fused epilogue: pair-select then exp, in-register reduction ----
    // C/D layout (32x32): col = anchor = ln (+tn*32), row = g = (reg&3) +
    // 8*(reg>>2) + 4*q (+tm*32 +wm*128). Regs 4j..4j+3 hold 4 consecutive g,
    // i.e. local column pairs kidx = wm*64 + tm*16 + 4j + 2q and kidx+1.
    float pe[2] = {0.f, 0.f}, pc[2] = {0.f, 0.f};
    #pragma unroll
    for (int tm = 0; tm < 4; ++tm) {
        #pragma unroll
        for (int j = 0; j < 4; ++j) {
            int kidx = wm * 64 + tm * 16 + 4 * j + 2 * q;   // local k in [0,128)
            float4 m0 = kms[kidx];
            float4 m1 = kms[kidx + 1];
            #pragma unroll
            for (int p = 0; p < 2; ++p) {
                float4 md = p ? m1 : m0;
                int c0 = __float_as_int(md.z);
                int re = 4 * j + 2 * p;     // even-g reg; odd is re+1
                #pragma unroll
                for (int tn = 0; tn < 2; ++tn) {
                    bool sel = (c0 >= anc[tn]);             // use column c0+1
                    float v = sel ? acc[tm][tn][re + 1] : acc[tm][tn][re];
                    float rj = sel ? md.y : md.x;
                    float logit = v * riv[tn] * rj;
                    pe[tn] += __expf(logit);
                    pc[tn] += (logit > pv[tn]) ? 1.f : 0.f;
                }
            }
        }
    }
    #pragma unroll
    for (int tn = 0; tn < 2; ++tn) {
        pe[tn] += __shfl_xor(pe[tn], 32);
        pc[tn] += __shfl_xor(pc[tn], 32);
        if (q == 0) {
            atomicAdd(&rowacc[anc[tn]], pe[tn]);
            atomicAdd(&rowacc[B_SZ + anc[tn]], pc[tn]);
        }
    }

    // ---- last-block finalize (merged k_final), acq-rel ticket, no fence ----
    __syncthreads();                        // drains every wave's atomics (vmcnt)
    if (tid == 0) {
        int t = __hip_atomic_fetch_add(&tickets[aTile], 1,
                                       __ATOMIC_ACQ_REL, __HIP_MEMORY_SCOPE_AGENT);
        doFin = (t == 15);                  // 16 blocks (gTiles) per aTile
    }
    __syncthreads();
    if (doFin) {
        float loss = 0.f, a1 = 0.f, a5 = 0.f;
        if (tid < 256) {
            int row = aBase + tid;
            float pes = __hip_atomic_load(&rowacc[row],
                                          __ATOMIC_RELAXED, __HIP_MEMORY_SCOPE_AGENT);
            float pcs = __hip_atomic_load(&rowacc[B_SZ + row],
                                          __ATOMIC_RELAXED, __HIP_MEMORY_SCOPE_AGENT);
            float pos = pv[0];              // unused fallback; real value below
            pos = pos_arr[row];
            loss = logf(__expf(pos) + pes) - pos;  // logsumexp - pos (bounded)
            a1 = (pcs < 0.5f) ? 1.f : 0.f;         // no neg strictly > pos
            a5 = (pcs < 4.5f) ? 1.f : 0.f;         // at most 4 negs > pos
        }
        for (int m = 1; m < 64; m <<= 1) {
            loss += __shfl_xor(loss, m);
            a1 += __shfl_xor(a1, m);
            a5 += __shfl_xor(a5, m);
        }
        if (l == 0) { red[0][w] = loss; red[1][w] = a1; red[2][w] = a5; }
        __syncthreads();
        if (tid == 0) {
            float L = 0.f, A1 = 0.f, A5 = 0.f;
            #pragma unroll
            for (int i = 0; i < 8; ++i) {
                L += red[0][i]; A1 += red[1][i]; A5 += red[2][i];
            }
            atomicAdd(&out[0], L / (float)B_SZ);
            atomicAdd(&out[1], A1 * (100.f / (float)B_SZ));
            atomicAdd(&out[2], A5 * (100.f / (float)B_SZ));
        }
    }
}

// ---------------------------------------------------------------------------
extern "C" void kernel_launch(void* const* d_in, const int* in_sizes, int n_in,
                              void* d_out, int out_size, void* d_ws, size_t ws_size,
                              hipStream_t stream)
{
    const float* zi = (const float*)d_in[0];
    const float* zj = (const float*)d_in[1];
    const int* perm = (const int*)d_in[2];
    float* out = (float*)d_out;

    // workspace layout (all 16B aligned)
    char* p = (char*)d_ws;
    unsigned char* A = (unsigned char*)p;    p += (size_t)B_SZ * D_SZ;          // 4 MB
    unsigned char* G = (unsigned char*)p;    p += (size_t)2 * K_SZ * D_SZ;      // 2 MB
    float* ri_arr = (float*)p;               p += (size_t)B_SZ * 4;
    float* pos_arr = (float*)p;              p += (size_t)B_SZ * 4;
    float4* kmeta = (float4*)p;              p += (size_t)K_SZ * 16;            // 32 KB
    float* rowacc = (float*)p;               p += (size_t)2 * B_SZ * 4;         // 64 KB
    int* tickets = (int*)p;                  p += 128;

    k_prep<<<2048 + 1024, 256, 0, stream>>>(zi, zj, perm, ri_arr, pos_arr, A,
                                            kmeta, G, rowacc, tickets, out);
    k_gemm<<<512, 512, 0, stream>>>(A, G, kmeta, ri_arr, pos_arr, rowacc,
                                    tickets, out);
}

// Round 4
// 111.242 us; speedup vs baseline: 1.7044x; 1.0758x over previous
//
#include <hip/hip_runtime.h>
#include <cstdint>

#define B_SZ 8192
#define D_SZ 512
#define K_SZ 2048
#define G_SZ 4096
#define EPSV 1e-8f
// 1/TEMP
#define INV_T 2.0f

typedef float floatx16 __attribute__((ext_vector_type(16)));
typedef int intx8 __attribute__((ext_vector_type(8)));

// async global->LDS, 16B per lane. LDS dest must be wave-uniform base + lane*16.
// R2 lesson: DMA cost scales with DISTINCT CACHE LINES per instruction (random
// 16-line gather = 126us; strided 16-line = 46us). R4: kb-major operand layout
// makes every STAGE instruction a dense 1KB burst (8 sequential lines).
__device__ __forceinline__ void async_cp16(const void* g, void* l) {
    typedef __attribute__((address_space(1))) unsigned int gds_t;
    typedef __attribute__((address_space(3))) unsigned int lds_t;
    __builtin_amdgcn_global_load_lds((gds_t*)(unsigned long long)g, (lds_t*)l, 16, 0, 0);
}

// pack 8 fp32 -> 8 fp8 e4m3 (OCP, RNE, saturating) as int2
__device__ __forceinline__ int2 pack_fp8x8(float4 a0, float4 a1) {
    int w0 = __builtin_amdgcn_cvt_pk_fp8_f32(a0.x, a0.y, 0, false);
    w0 = __builtin_amdgcn_cvt_pk_fp8_f32(a0.z, a0.w, w0, true);
    int w1 = __builtin_amdgcn_cvt_pk_fp8_f32(a1.x, a1.y, 0, false);
    w1 = __builtin_amdgcn_cvt_pk_fp8_f32(a1.z, a1.w, w1, true);
    return make_int2(w0, w1);
}

// ---------------------------------------------------------------------------
// Kernel 1: merged prep+gather (R1 structure). NEW: A and G stored K-BLOCK-
// MAJOR: A_t[kb][row][64], G_t[kb][g][64] (kb = 64-byte K-block 0..7), so
// k_gemm's global_load_lds sources are dense 1KB bursts.
//  lane l holds fp8 bytes [8l, 8l+8) of its row -> kb = l>>3, chunk byte
//  (l&7)*8 within the row's 64B slice.
// ---------------------------------------------------------------------------
__global__ __launch_bounds__(256) void k_prep(
    const float* __restrict__ zi, const float* __restrict__ zj,
    const int* __restrict__ perm,
    float* __restrict__ ri_arr, float* __restrict__ pos_arr,
    unsigned char* __restrict__ A,
    float4* __restrict__ kmeta, unsigned char* __restrict__ G,
    float* __restrict__ rowacc, float* __restrict__ out)
{
    int w = threadIdx.x >> 6, l = threadIdx.x & 63;
    if (blockIdx.x < 2048) {
        if (blockIdx.x < 64)
            rowacc[blockIdx.x * 256 + threadIdx.x] = 0.f;   // pe[8192] ++ pc[8192]
        if (blockIdx.x == 0 && threadIdx.x < 3) out[threadIdx.x] = 0.f;
        int row = blockIdx.x * 4 + w;
        const float4* zi4 = (const float4*)(zi + (size_t)row * D_SZ);
        const float4* zj4 = (const float4*)(zj + (size_t)row * D_SZ);
        float4 a0 = zi4[2 * l], a1 = zi4[2 * l + 1];
        float4 b0 = zj4[2 * l], b1 = zj4[2 * l + 1];
        float si = a0.x * a0.x + a0.y * a0.y + a0.z * a0.z + a0.w * a0.w
                 + a1.x * a1.x + a1.y * a1.y + a1.z * a1.z + a1.w * a1.w;
        float sj = b0.x * b0.x + b0.y * b0.y + b0.z * b0.z + b0.w * b0.w
                 + b1.x * b1.x + b1.y * b1.y + b1.z * b1.z + b1.w * b1.w;
        float dd = a0.x * b0.x + a0.y * b0.y + a0.z * b0.z + a0.w * b0.w
                 + a1.x * b1.x + a1.y * b1.y + a1.z * b1.z + a1.w * b1.w;
        for (int m = 1; m < 64; m <<= 1) {
            si += __shfl_xor(si, m);
            sj += __shfl_xor(sj, m);
            dd += __shfl_xor(dd, m);
        }
        if (l == 0) {
            float ni = sqrtf(si), nj = sqrtf(sj);
            ri_arr[row] = INV_T / fmaxf(ni, 1e-6f);   // norms ~22; eps never binds
            pos_arr[row] = dd / fmaxf(ni * nj, EPSV) * INV_T;
        }
        // kb-major store: A_t[l>>3][row][ (l&7)*8 .. +8 )
        *(int2*)(A + ((size_t)(l >> 3) * B_SZ + row) * 64 + (l & 7) * 8)
            = pack_fp8x8(a0, a1);
    } else {
        __shared__ float srj[4];
        int g = (blockIdx.x - 2048) * 4 + w;        // 0..4095
        int c0 = perm[g >> 1];
        int c = c0 + (g & 1);                       // actual z_j row
        const float4* src = (const float4*)(zj + (size_t)c * D_SZ);
        float4 a0 = src[2 * l], a1 = src[2 * l + 1];
        float s = a0.x * a0.x + a0.y * a0.y + a0.z * a0.z + a0.w * a0.w
                + a1.x * a1.x + a1.y * a1.y + a1.z * a1.z + a1.w * a1.w;
        for (int m = 1; m < 64; m <<= 1) s += __shfl_xor(s, m);
        if (l == 0) srj[w] = 1.0f / fmaxf(sqrtf(s), 1e-6f);
        __syncthreads();
        if ((w & 1) == 0 && l == 0)
            kmeta[g >> 1] = make_float4(srj[w], srj[w + 1],
                                        __int_as_float(c0), 0.f);
        *(int2*)(G + ((size_t)(l >> 3) * G_SZ + g) * 64 + (l & 7) * 8)
            = pack_fp8x8(a0, a1);
    }
}

// ---------------------------------------------------------------------------
// Kernel 2 (R14): MX-fp8 MFMA GEMM, S^T = G . A^T, 256x256 tile, 8 waves,
// 3-deep LDS ring + counted vmcnt(4) + one raw s_barrier per K-step (exact
// R1 schedule, 112.3us verified). Changes vs R1:
//  - kb-major global layout: every STAGE global_load_lds reads a dense 1KB
//    burst (8 sequential cache lines) instead of 16 strided 64B segments.
//    LDS layout / swizzle / frag reads byte-identical to R1.
//  - epilogue globals hoisted to prologue (kms -> LDS, ri/pos -> regs),
//    drained with vmcnt(0) before STAGE 0 -> counted vmcnt is airtight.
//  - separate k_final retained (R3's merged finalize regressed).
// ---------------------------------------------------------------------------
__global__ __launch_bounds__(512, 2) void k_gemm(
    const unsigned char* __restrict__ A,    // [8][8192][64] fp8  kb-major
    const unsigned char* __restrict__ G,    // [8][4096][64] fp8  kb-major
    const float4* __restrict__ kmeta,       // [2048]  {rj0, rj1, c0f, -}
    const float* __restrict__ ri_arr,       // [8192]  INV_T/ni
    const float* __restrict__ pos_arr,      // [8192]
    float* __restrict__ rowacc)             // [2][8192] atomic accumulators
{
    __shared__ unsigned char Asl[3][256 * 64];   // anchor tiles, 16 KB each
    __shared__ unsigned char Gsl[3][256 * 64];   // g tiles
    __shared__ float4 kms[128];                  // this gTile's kmeta slice
    const int tid = threadIdx.x;
    const int l = tid & 63, w = tid >> 6;
    const int wm = w >> 2, wn = w & 3;      // wm: g-half (0..1), wn: anchor quarter
    const int ln = l & 31, q = l >> 5;      // 32x32 MFMA lane decomposition

    // XCD-aware tile mapping: 512 blocks; xcd = bid&7 owns g-panels xcd*2..+2
    const int bid = blockIdx.x;
    const int xcd = bid & 7;
    const int slot = bid >> 3;              // 0..63
    const int gTile = xcd * 2 + (slot & 1); // 0..15 (G row panel, 256 rows)
    const int aTile = slot >> 1;            // 0..31 (anchor panel, 256 rows)
    const int gBase = gTile * 256;
    const int aBase = aTile * 256;

    // staging offsets (bytes) WITHIN one K-block slab; 1024 16B-chunks per
    // array per K-block (2 iters x 512 threads). Same XOR swizzle (0 confl).
    size_t aOff[2], gOff[2];
    int ldsOff[2];
    #pragma unroll
    for (int it = 0; it < 2; ++it) {
        int fc = it * 512 + tid;            // 16B chunk 0..1023
        int r = fc >> 2, s = fc & 3;
        int scc = s ^ ((r ^ (r >> 2)) & 3); // XOR swizzle source 16B chunk
        aOff[it] = (size_t)(aBase + r) * 64 + scc * 16;
        gOff[it] = (size_t)(gBase + r) * 64 + scc * 16;
        ldsOff[it] = fc * 16;
    }

    floatx16 acc[4][2] = {};                // [tm: g-subtile][tn: anchor-subtile]

    // frag read addresses (bytes in a 16 KB buffer): lane needs k-bytes
    // [q*32, q*32+32) of its row = pre-swizzle chunks {2q, 2q+1}
    int aAddr[2][2], gAddr[4][2];
    #pragma unroll
    for (int tn = 0; tn < 2; ++tn) {
        int ar = wn * 64 + tn * 32 + ln;    // anchor row in tile (N-operand)
        int xa = (ar ^ (ar >> 2)) & 3;
        aAddr[tn][0] = ar * 64 + ((2 * q) ^ xa) * 16;
        aAddr[tn][1] = ar * 64 + ((2 * q + 1) ^ xa) * 16;
    }
    #pragma unroll
    for (int tm = 0; tm < 4; ++tm) {
        int gr = wm * 128 + tm * 32 + ln;   // g row in tile (M-operand)
        int xg = (gr ^ (gr >> 2)) & 3;
        gAddr[tm][0] = gr * 64 + ((2 * q) ^ xg) * 16;
        gAddr[tm][1] = gr * 64 + ((2 * q + 1) ^ xg) * 16;
    }

    // ---- prologue: ALL global loads the epilogue needs, then drain ----
    int anc[2]; float riv[2], pv[2];
    #pragma unroll
    for (int tn = 0; tn < 2; ++tn) {
        anc[tn] = aBase + wn * 64 + tn * 32 + ln;
        riv[tn] = ri_arr[anc[tn]];          // INV_T / ni
        pv[tn] = pos_arr[anc[tn]];
    }
    float4 kv = make_float4(0.f, 0.f, 0.f, 0.f);
    if (tid < 128) kv = kmeta[gTile * 128 + tid];
    // Drain: from here on, vmcnt counts ONLY the 4-load STAGE groups.
    asm volatile("s_waitcnt vmcnt(0)" ::: "memory");
    __builtin_amdgcn_sched_barrier(0);
    if (tid < 128) kms[tid] = kv;           // own lgkmcnt(0)@kb0 + barrier@kb1
                                            // order this before all epilogue reads

    // stage K-block kb into ring buffer `buf` (4 async_cp16 per thread);
    // source slab for kb is contiguous: A + kb*8192*64, G + kb*4096*64.
    auto STAGE = [&](int buf, int kb) {
        const unsigned char* As = A + (size_t)kb * B_SZ * 64;
        const unsigned char* Gs = G + (size_t)kb * G_SZ * 64;
        #pragma unroll
        for (int it = 0; it < 2; ++it) {
            async_cp16(As + aOff[it], &Asl[buf][ldsOff[it]]);
            async_cp16(Gs + gOff[it], &Gsl[buf][ldsOff[it]]);
        }
    };

    // prologue: fill first two ring slots (lookahead = 2 K-steps, R1 exact)
    STAGE(0, 0);
    STAGE(1, 1);

    #pragma unroll
    for (int kb = 0; kb < 8; ++kb) {
        const int cur = kb % 3;
        // wait for buf[cur]'s 4 stage loads (the newest 4 = next K-block stay
        // in flight -- NEVER drain vmcnt to 0 mid-loop). vmcnt is in-order.
        if (kb < 7) {
            asm volatile("s_waitcnt vmcnt(4)" ::: "memory");
        } else {
            asm volatile("s_waitcnt vmcnt(0)" ::: "memory");
        }
        __builtin_amdgcn_s_barrier();       // ALL waves' DMA for cur landed;
                                            // all waves done reading the slot we overwrite
        if (kb < 6) STAGE((kb + 2) % 3, kb + 2);   // overwrite oldest slot

        intx8 af[2], gf[4];
        #pragma unroll
        for (int tn = 0; tn < 2; ++tn) {
            int4 lo = *(const int4*)&Asl[cur][aAddr[tn][0]];
            int4 hi = *(const int4*)&Asl[cur][aAddr[tn][1]];
            af[tn][0] = lo.x; af[tn][1] = lo.y; af[tn][2] = lo.z; af[tn][3] = lo.w;
            af[tn][4] = hi.x; af[tn][5] = hi.y; af[tn][6] = hi.z; af[tn][7] = hi.w;
        }
        #pragma unroll
        for (int tm = 0; tm < 4; ++tm) {
            int4 lo = *(const int4*)&Gsl[cur][gAddr[tm][0]];
            int4 hi = *(const int4*)&Gsl[cur][gAddr[tm][1]];
            gf[tm][0] = lo.x; gf[tm][1] = lo.y; gf[tm][2] = lo.z; gf[tm][3] = lo.w;
            gf[tm][4] = hi.x; gf[tm][5] = hi.y; gf[tm][6] = hi.z; gf[tm][7] = hi.w;
        }
        // reads must retire before next iter's barrier (so STAGE can overwrite)
        asm volatile("s_waitcnt lgkmcnt(0)" ::: "memory");
        __builtin_amdgcn_sched_barrier(0);  // rule #18: pin MFMA after the wait

        __builtin_amdgcn_s_setprio(1);      // T5: favor the MFMA cluster
        #pragma unroll
        for (int tm = 0; tm < 4; ++tm)
            #pragma unroll
            for (int tn = 0; tn < 2; ++tn)
                acc[tm][tn] = __builtin_amdgcn_mfma_scale_f32_32x32x64_f8f6f4(
                    gf[tm], af[tn], acc[tm][tn],
                    0, 0,                       // cbsz/blgp = fp8 e4m3
                    0, 0x7f7f7f7f,              // scale A: all-ones (2^0)
                    0, 0x7f7f7f7f);             // scale B: all-ones (2^0)
        __builtin_amdgcn_s_setprio(0);
    }

    // ---- fused epilogue: pair-select then exp, in-register reduction ----
    // C/D layout (32x32): col = anchor = ln (+tn*32), row = g = (reg&3) +
    // 8*(reg>>2) + 4*q (+tm*32 +wm*128). Regs 4j..4j+3 hold 4 consecutive g,
    // i.e. local column pairs kidx = wm*64 + tm*16 + 4j + 2q and kidx+1.
    float pe[2] = {0.f, 0.f}, pc[2] = {0.f, 0.f};
    #pragma unroll
    for (int tm = 0; tm < 4; ++tm) {
        #pragma unroll
        for (int j = 0; j < 4; ++j) {
            int kidx = wm * 64 + tm * 16 + 4 * j + 2 * q;   // local k in [0,128)
            float4 m0 = kms[kidx];
            float4 m1 = kms[kidx + 1];
            #pragma unroll
            for (int p = 0; p < 2; ++p) {
                float4 md = p ? m1 : m0;
                int c0 = __float_as_int(md.z);
                int re = 4 * j + 2 * p;     // even-g reg; odd is re+1
                #pragma unroll
                for (int tn = 0; tn < 2; ++tn) {
                    bool sel = (c0 >= anc[tn]);             // use column c0+1
                    float v = sel ? acc[tm][tn][re + 1] : acc[tm][tn][re];
                    float rj = sel ? md.y : md.x;
                    float logit = v * riv[tn] * rj;
                    pe[tn] += __expf(logit);
                    pc[tn] += (logit > pv[tn]) ? 1.f : 0.f;
                }
            }
        }
    }
    #pragma unroll
    for (int tn = 0; tn < 2; ++tn) {
        pe[tn] += __shfl_xor(pe[tn], 32);
        pc[tn] += __shfl_xor(pc[tn], 32);
        if (q == 0) {
            atomicAdd(&rowacc[anc[tn]], pe[tn]);
            atomicAdd(&rowacc[B_SZ + anc[tn]], pc[tn]);
        }
    }
}

// ---------------------------------------------------------------------------
// Kernel 3: tiny finalize — one thread per row, then block+global reduce.
// ---------------------------------------------------------------------------
__global__ __launch_bounds__(256) void k_final(
    const float* __restrict__ rowacc, const float* __restrict__ pos_arr,
    float* __restrict__ out)
{
    int row = blockIdx.x * 256 + threadIdx.x;
    float pe = rowacc[row];
    float pc = rowacc[B_SZ + row];
    float pos = pos_arr[row];
    float loss = logf(__expf(pos) + pe) - pos;   // logsumexp - pos (logits bounded)
    float a1 = (pc < 0.5f) ? 1.f : 0.f;          // no neg strictly > pos
    float a5 = (pc < 4.5f) ? 1.f : 0.f;          // at most 4 negs strictly > pos
    for (int m = 1; m < 64; m <<= 1) {
        loss += __shfl_xor(loss, m);
        a1 += __shfl_xor(a1, m);
        a5 += __shfl_xor(a5, m);
    }
    __shared__ float red[3][4];
    int w = threadIdx.x >> 6, l = threadIdx.x & 63;
    if (l == 0) { red[0][w] = loss; red[1][w] = a1; red[2][w] = a5; }
    __syncthreads();
    if (threadIdx.x == 0) {
        float L = red[0][0] + red[0][1] + red[0][2] + red[0][3];
        float A1 = red[1][0] + red[1][1] + red[1][2] + red[1][3];
        float A5 = red[2][0] + red[2][1] + red[2][2] + red[2][3];
        atomicAdd(&out[0], L / (float)B_SZ);
        atomicAdd(&out[1], A1 * (100.f / (float)B_SZ));
        atomicAdd(&out[2], A5 * (100.f / (float)B_SZ));
    }
}

// ---------------------------------------------------------------------------
extern "C" void kernel_launch(void* const* d_in, const int* in_sizes, int n_in,
                              void* d_out, int out_size, void* d_ws, size_t ws_size,
                              hipStream_t stream)
{
    const float* zi = (const float*)d_in[0];
    const float* zj = (const float*)d_in[1];
    const int* perm = (const int*)d_in[2];
    float* out = (float*)d_out;

    // workspace layout (all 16B aligned)
    char* p = (char*)d_ws;
    unsigned char* A = (unsigned char*)p;    p += (size_t)B_SZ * D_SZ;          // 4 MB, kb-major
    unsigned char* G = (unsigned char*)p;    p += (size_t)2 * K_SZ * D_SZ;      // 2 MB, kb-major
    float* ri_arr = (float*)p;               p += (size_t)B_SZ * 4;
    float* pos_arr = (float*)p;              p += (size_t)B_SZ * 4;
    float4* kmeta = (float4*)p;              p += (size_t)K_SZ * 16;            // 32 KB
    float* rowacc = (float*)p;               p += (size_t)2 * B_SZ * 4;         // 64 KB

    k_prep<<<2048 + 1024, 256, 0, stream>>>(zi, zj, perm, ri_arr, pos_arr, A,
                                            kmeta, G, rowacc, out);
    k_gemm<<<512, 512, 0, stream>>>(A, G, kmeta, ri_arr, pos_arr, rowacc);
    k_final<<<32, 256, 0, stream>>>(rowacc, pos_arr, out);
}

// Round 5
// 110.201 us; speedup vs baseline: 1.7205x; 1.0094x over previous
//
#include <hip/hip_runtime.h>
#include <cstdint>

#define B_SZ 8192
#define D_SZ 512
#define K_SZ 2048
#define G_SZ 4096
#define EPSV 1e-8f
// 1/TEMP
#define INV_T 2.0f

typedef float floatx16 __attribute__((ext_vector_type(16)));
typedef int intx8 __attribute__((ext_vector_type(8)));

// pack 8 fp32 -> 8 fp8 e4m3 (OCP, RNE, saturating) as int2
__device__ __forceinline__ int2 pack_fp8x8(float4 a0, float4 a1) {
    int w0 = __builtin_amdgcn_cvt_pk_fp8_f32(a0.x, a0.y, 0, false);
    w0 = __builtin_amdgcn_cvt_pk_fp8_f32(a0.z, a0.w, w0, true);
    int w1 = __builtin_amdgcn_cvt_pk_fp8_f32(a1.x, a1.y, 0, false);
    w1 = __builtin_amdgcn_cvt_pk_fp8_f32(a1.z, a1.w, w1, true);
    return make_int2(w0, w1);
}

// ---------------------------------------------------------------------------
// Kernel 1: merged prep+gather (unchanged from R4, verified). A and G stored
// K-BLOCK-MAJOR: A_t[kb][row][64], G_t[kb][g][64] (kb = 64-byte K-block 0..7).
// ---------------------------------------------------------------------------
__global__ __launch_bounds__(256) void k_prep(
    const float* __restrict__ zi, const float* __restrict__ zj,
    const int* __restrict__ perm,
    float* __restrict__ ri_arr, float* __restrict__ pos_arr,
    unsigned char* __restrict__ A,
    float4* __restrict__ kmeta, unsigned char* __restrict__ G,
    float* __restrict__ rowacc, float* __restrict__ out)
{
    int w = threadIdx.x >> 6, l = threadIdx.x & 63;
    if (blockIdx.x < 2048) {
        if (blockIdx.x < 64)
            rowacc[blockIdx.x * 256 + threadIdx.x] = 0.f;   // pe[8192] ++ pc[8192]
        if (blockIdx.x == 0 && threadIdx.x < 3) out[threadIdx.x] = 0.f;
        int row = blockIdx.x * 4 + w;
        const float4* zi4 = (const float4*)(zi + (size_t)row * D_SZ);
        const float4* zj4 = (const float4*)(zj + (size_t)row * D_SZ);
        float4 a0 = zi4[2 * l], a1 = zi4[2 * l + 1];
        float4 b0 = zj4[2 * l], b1 = zj4[2 * l + 1];
        float si = a0.x * a0.x + a0.y * a0.y + a0.z * a0.z + a0.w * a0.w
                 + a1.x * a1.x + a1.y * a1.y + a1.z * a1.z + a1.w * a1.w;
        float sj = b0.x * b0.x + b0.y * b0.y + b0.z * b0.z + b0.w * b0.w
                 + b1.x * b1.x + b1.y * b1.y + b1.z * b1.z + b1.w * b1.w;
        float dd = a0.x * b0.x + a0.y * b0.y + a0.z * b0.z + a0.w * b0.w
                 + a1.x * b1.x + a1.y * b1.y + a1.z * b1.z + a1.w * b1.w;
        for (int m = 1; m < 64; m <<= 1) {
            si += __shfl_xor(si, m);
            sj += __shfl_xor(sj, m);
            dd += __shfl_xor(dd, m);
        }
        if (l == 0) {
            float ni = sqrtf(si), nj = sqrtf(sj);
            ri_arr[row] = INV_T / fmaxf(ni, 1e-6f);   // norms ~22; eps never binds
            pos_arr[row] = dd / fmaxf(ni * nj, EPSV) * INV_T;
        }
        // kb-major store: A_t[l>>3][row][ (l&7)*8 .. +8 )
        *(int2*)(A + ((size_t)(l >> 3) * B_SZ + row) * 64 + (l & 7) * 8)
            = pack_fp8x8(a0, a1);
    } else {
        __shared__ float srj[4];
        int g = (blockIdx.x - 2048) * 4 + w;        // 0..4095
        int c0 = perm[g >> 1];
        int c = c0 + (g & 1);                       // actual z_j row
        const float4* src = (const float4*)(zj + (size_t)c * D_SZ);
        float4 a0 = src[2 * l], a1 = src[2 * l + 1];
        float s = a0.x * a0.x + a0.y * a0.y + a0.z * a0.z + a0.w * a0.w
                + a1.x * a1.x + a1.y * a1.y + a1.z * a1.z + a1.w * a1.w;
        for (int m = 1; m < 64; m <<= 1) s += __shfl_xor(s, m);
        if (l == 0) srj[w] = 1.0f / fmaxf(sqrtf(s), 1e-6f);
        __syncthreads();
        if ((w & 1) == 0 && l == 0)
            kmeta[g >> 1] = make_float4(srj[w], srj[w + 1],
                                        __int_as_float(c0), 0.f);
        *(int2*)(G + ((size_t)(l >> 3) * G_SZ + g) * 64 + (l & 7) * 8)
            = pack_fp8x8(a0, a1);
    }
}

// ---------------------------------------------------------------------------
// Kernel 2 (R15): REG-STAGED GEMM — the discriminating experiment.
// S^T = G . A^T, tile 256(g) x 128(anchor), 1024 blocks x 512 thr (8 waves).
// Staging: global_load_dwordx4 -> VGPR (issued one K-step early; the vector
// VMEM path pipelines outstanding loads, unlike -- hypothesized -- the
// global_load_lds DMA engine that pinned every prior config at ~40-46us),
// then ds_write_b128 into a 2-slot LDS ring, write-late (T14).
// LDS content layout and frag reads are byte-identical to R4: the XOR chunk
// swizzle moves from source-permute to ds_write DEST-permute.
// One raw s_barrier + lgkmcnt(0) per K-step; NO vmcnt asm (compiler inserts
// the exact counted wait for the load->ds_write dependency).
// Hazard check (2-slot ring, 1 barrier/step): buf[cur] written at step kb
// (drained by lgkmcnt before B_kb); read after B_kb, reads drained by the
// post-read lgkmcnt before each wave reaches B_{kb+1}; next write to
// buf[cur] is at step kb+2, after B_{kb+1}. Safe.
// Regs: acc 64 AGPR + ~120 VGPR (incl. 6 int4 staging) -> 2 waves/SIMD kept.
// ---------------------------------------------------------------------------
__global__ __launch_bounds__(512, 2) void k_gemm(
    const unsigned char* __restrict__ A,    // [8][8192][64] fp8  kb-major
    const unsigned char* __restrict__ G,    // [8][4096][64] fp8  kb-major
    const float4* __restrict__ kmeta,       // [2048]  {rj0, rj1, c0f, -}
    const float* __restrict__ ri_arr,       // [8192]  INV_T/ni
    const float* __restrict__ pos_arr,      // [8192]
    float* __restrict__ rowacc)             // [2][8192] atomic accumulators
{
    __shared__ unsigned char Asl[2][128 * 64];   // anchor tiles, 8 KB each
    __shared__ unsigned char Gsl[2][256 * 64];   // g tiles, 16 KB each
    __shared__ float4 kms[128];                  // this gTile's kmeta slice
    const int tid = threadIdx.x;
    const int l = tid & 63, w = tid >> 6;
    const int wm = w >> 2, wn = w & 3;      // wm: g-half (0..1), wn: anchor quarter
    const int ln = l & 31, q = l >> 5;      // 32x32 MFMA lane decomposition

    // XCD-aware tile mapping: 1024 blocks; xcd = bid&7 owns g-panels xcd*2..+2
    const int bid = blockIdx.x;
    const int xcd = bid & 7;
    const int slot = bid >> 3;              // 0..127
    const int gTile = xcd * 2 + (slot & 1); // 0..15 (G row panel, 256 rows)
    const int aTile = slot >> 1;            // 0..63 (anchor panel, 128 rows)
    const int gBase = gTile * 256;
    const int aBase = aTile * 128;

    // LDS dest for a linear 16B chunk fc: row r = fc>>2, col s = fc&3 stored
    // at col s ^ ((r^(r>>2))&3). Same LDS content as R4's source-permute.
    auto lds_slot = [](int fc) {
        int r = fc >> 2, s = fc & 3;
        int sc = s ^ ((r ^ (r >> 2)) & 3);
        return r * 64 + sc * 16;
    };
    const int aDst  = lds_slot(tid);         // A: 512 chunks, one per thread
    const int gDst0 = lds_slot(tid);         // G: 1024 chunks, two per thread
    const int gDst1 = lds_slot(tid + 512);

    floatx16 acc[4] = {};                   // [tm: g-subtile]; anchor frag = 1

    // frag read addresses (bytes): lane needs pre-swizzle chunks {2q, 2q+1}
    int aAddr[2], gAddr[4][2];
    {
        int ar = wn * 32 + ln;              // anchor row in tile (N-operand)
        int xa = (ar ^ (ar >> 2)) & 3;
        aAddr[0] = ar * 64 + ((2 * q) ^ xa) * 16;
        aAddr[1] = ar * 64 + ((2 * q + 1) ^ xa) * 16;
    }
    #pragma unroll
    for (int tm = 0; tm < 4; ++tm) {
        int gr = wm * 128 + tm * 32 + ln;   // g row in tile (M-operand)
        int xg = (gr ^ (gr >> 2)) & 3;
        gAddr[tm][0] = gr * 64 + ((2 * q) ^ xg) * 16;
        gAddr[tm][1] = gr * 64 + ((2 * q + 1) ^ xg) * 16;
    }

    // ---- prologue: epilogue data + kms, plus first staging group ----
    const int anc = aBase + wn * 32 + ln;
    const float riv = ri_arr[anc];          // INV_T / ni
    const float pv = pos_arr[anc];
    if (tid < 128) kms[tid] = kmeta[gTile * 128 + tid];

    // staging registers, ping-pong across unrolled iterations (static idx)
    int4 ra[2], rg0[2], rg1[2];
    ra[0]  = *(const int4*)(A + ((size_t)0 * B_SZ + aBase) * 64 + tid * 16);
    rg0[0] = *(const int4*)(G + ((size_t)0 * G_SZ + gBase) * 64 + tid * 16);
    rg1[0] = *(const int4*)(G + ((size_t)0 * G_SZ + gBase) * 64 + (tid + 512) * 16);

    #pragma unroll
    for (int kb = 0; kb < 8; ++kb) {
        const int cur = kb & 1;
        // write staged group kb into buf[cur]; compiler inserts the counted
        // vmcnt wait for exactly these three loads.
        *(int4*)&Asl[cur][aDst]  = ra[cur];
        *(int4*)&Gsl[cur][gDst0] = rg0[cur];
        *(int4*)&Gsl[cur][gDst1] = rg1[cur];
        // issue group kb+1 (vector loads; fully pipelined, fly across barrier)
        if (kb < 7) {
            const int nxt = cur ^ 1;
            ra[nxt]  = *(const int4*)(A + ((size_t)(kb + 1) * B_SZ + aBase) * 64 + tid * 16);
            rg0[nxt] = *(const int4*)(G + ((size_t)(kb + 1) * G_SZ + gBase) * 64 + tid * 16);
            rg1[nxt] = *(const int4*)(G + ((size_t)(kb + 1) * G_SZ + gBase) * 64 + (tid + 512) * 16);
        }
        // ds_writes must be LDS-visible before the barrier
        asm volatile("s_waitcnt lgkmcnt(0)" ::: "memory");
        __builtin_amdgcn_sched_barrier(0);
        __builtin_amdgcn_s_barrier();       // buf[cur] full for all waves

        intx8 af, gf[4];
        {
            int4 lo = *(const int4*)&Asl[cur][aAddr[0]];
            int4 hi = *(const int4*)&Asl[cur][aAddr[1]];
            af[0] = lo.x; af[1] = lo.y; af[2] = lo.z; af[3] = lo.w;
            af[4] = hi.x; af[5] = hi.y; af[6] = hi.z; af[7] = hi.w;
        }
        #pragma unroll
        for (int tm = 0; tm < 4; ++tm) {
            int4 lo = *(const int4*)&Gsl[cur][gAddr[tm][0]];
            int4 hi = *(const int4*)&Gsl[cur][gAddr[tm][1]];
            gf[tm][0] = lo.x; gf[tm][1] = lo.y; gf[tm][2] = lo.z; gf[tm][3] = lo.w;
            gf[tm][4] = hi.x; gf[tm][5] = hi.y; gf[tm][6] = hi.z; gf[tm][7] = hi.w;
        }
        // reads retire here -> next-next write to this slot (after B_{kb+1})
        // can never race them; also rule #18 fence before the MFMA cluster.
        asm volatile("s_waitcnt lgkmcnt(0)" ::: "memory");
        __builtin_amdgcn_sched_barrier(0);

        __builtin_amdgcn_s_setprio(1);      // T5
        #pragma unroll
        for (int tm = 0; tm < 4; ++tm)
            acc[tm] = __builtin_amdgcn_mfma_scale_f32_32x32x64_f8f6f4(
                gf[tm], af, acc[tm],
                0, 0,                       // cbsz/blgp = fp8 e4m3
                0, 0x7f7f7f7f,              // scale A: all-ones (2^0)
                0, 0x7f7f7f7f);             // scale B: all-ones (2^0)
        __builtin_amdgcn_s_setprio(0);
    }

    // ---- fused epilogue: pair-select then exp, in-register reduction ----
    // C/D layout (32x32): col = anchor = ln, row = g = (reg&3) + 8*(reg>>2)
    // + 4*q (+tm*32 +wm*128). Regs 4j..4j+3 hold 4 consecutive g, i.e. local
    // column pairs kidx = wm*64 + tm*16 + 4j + 2q and kidx+1.
    float pe = 0.f, pc = 0.f;
    #pragma unroll
    for (int tm = 0; tm < 4; ++tm) {
        #pragma unroll
        for (int j = 0; j < 4; ++j) {
            int kidx = wm * 64 + tm * 16 + 4 * j + 2 * q;   // local k in [0,128)
            float4 m0 = kms[kidx];
            float4 m1 = kms[kidx + 1];
            #pragma unroll
            for (int p = 0; p < 2; ++p) {
                float4 md = p ? m1 : m0;
                int c0 = __float_as_int(md.z);
                int re = 4 * j + 2 * p;     // even-g reg; odd is re+1
                bool sel = (c0 >= anc);                 // use column c0+1
                float v = sel ? acc[tm][re + 1] : acc[tm][re];
                float rj = sel ? md.y : md.x;
                float logit = v * riv * rj;
                pe += __expf(logit);
                pc += (logit > pv) ? 1.f : 0.f;
            }
        }
    }
    pe += __shfl_xor(pe, 32);
    pc += __shfl_xor(pc, 32);
    if (q == 0) {
        atomicAdd(&rowacc[anc], pe);
        atomicAdd(&rowacc[B_SZ + anc], pc);
    }
}

// ---------------------------------------------------------------------------
// Kernel 3: tiny finalize — one thread per row, then block+global reduce.
// ---------------------------------------------------------------------------
__global__ __launch_bounds__(256) void k_final(
    const float* __restrict__ rowacc, const float* __restrict__ pos_arr,
    float* __restrict__ out)
{
    int row = blockIdx.x * 256 + threadIdx.x;
    float pe = rowacc[row];
    float pc = rowacc[B_SZ + row];
    float pos = pos_arr[row];
    float loss = logf(__expf(pos) + pe) - pos;   // logsumexp - pos (logits bounded)
    float a1 = (pc < 0.5f) ? 1.f : 0.f;          // no neg strictly > pos
    float a5 = (pc < 4.5f) ? 1.f : 0.f;          // at most 4 negs strictly > pos
    for (int m = 1; m < 64; m <<= 1) {
        loss += __shfl_xor(loss, m);
        a1 += __shfl_xor(a1, m);
        a5 += __shfl_xor(a5, m);
    }
    __shared__ float red[3][4];
    int w = threadIdx.x >> 6, l = threadIdx.x & 63;
    if (l == 0) { red[0][w] = loss; red[1][w] = a1; red[2][w] = a5; }
    __syncthreads();
    if (threadIdx.x == 0) {
        float L = red[0][0] + red[0][1] + red[0][2] + red[0][3];
        float A1 = red[1][0] + red[1][1] + red[1][2] + red[1][3];
        float A5 = red[2][0] + red[2][1] + red[2][2] + red[2][3];
        atomicAdd(&out[0], L / (float)B_SZ);
        atomicAdd(&out[1], A1 * (100.f / (float)B_SZ));
        atomicAdd(&out[2], A5 * (100.f / (float)B_SZ));
    }
}

// ---------------------------------------------------------------------------
extern "C" void kernel_launch(void* const* d_in, const int* in_sizes, int n_in,
                              void* d_out, int out_size, void* d_ws, size_t ws_size,
                              hipStream_t stream)
{
    const float* zi = (const float*)d_in[0];
    const float* zj = (const float*)d_in[1];
    const int* perm = (const int*)d_in[2];
    float* out = (float*)d_out;

    // workspace layout (all 16B aligned)
    char* p = (char*)d_ws;
    unsigned char* A = (unsigned char*)p;    p += (size_t)B_SZ * D_SZ;          // 4 MB, kb-major
    unsigned char* G = (unsigned char*)p;    p += (size_t)2 * K_SZ * D_SZ;      // 2 MB, kb-major
    float* ri_arr = (float*)p;               p += (size_t)B_SZ * 4;
    float* pos_arr = (float*)p;              p += (size_t)B_SZ * 4;
    float4* kmeta = (float4*)p;              p += (size_t)K_SZ * 16;            // 32 KB
    float* rowacc = (float*)p;               p += (size_t)2 * B_SZ * 4;         // 64 KB

    k_prep<<<2048 + 1024, 256, 0, stream>>>(zi, zj, perm, ri_arr, pos_arr, A,
                                            kmeta, G, rowacc, out);
    k_gemm<<<1024, 512, 0, stream>>>(A, G, kmeta, ri_arr, pos_arr, rowacc);
    k_final<<<32, 256, 0, stream>>>(rowacc, pos_arr, out);
}